// Round 13
// baseline (535.334 us; speedup 1.0000x reference)
//
#include <hip/hip_runtime.h>

#define BATCH 65536
#define DIM 128
#define NPROTO 512
#define ODIM 8

#define ROWS 64            // rows (batch elements) per block; lane == row
#define THREADS 512        // 8 waves; wave w owns protos [w*64, w*64+64)
#define XSTRIDE 132        // 128 + 4 pad floats -> 33 x 16B units for ds_read_b128

// wT layout: proto p = wb*64 + oo*8 + j   (wb=wave block 0..7, oo=octet 0..7, j=0..7)
//            dim   d = c*4 + d'           (c=chunk 0..31, d'=0..3)
// offset(p,d) = wb*8192 + oo*1024 + c*32 + j*4 + d'
// => per (wb,oo,c): 128 contiguous bytes holding 8 protos x 4 dims

// ---------------- prep: pack w = proto*rel^2 into wT; psq[p] = sum_d rel^2*proto^2
__global__ void grlvq_prep(const float* __restrict__ proto,
                           const float* __restrict__ rel,
                           float* __restrict__ wT,
                           float* __restrict__ psq) {
    int p = blockIdx.x * blockDim.x + threadIdx.x;
    if (p >= NPROTO) return;
    const int wb = p >> 6, oo = (p >> 3) & 7, j = p & 7;
    float acc = 0.f;
    #pragma unroll 8
    for (int d = 0; d < DIM; ++d) {
        float r = rel[d];
        float r2 = r * r;
        float v = proto[p * DIM + d];
        wT[wb * 8192 + oo * 1024 + (d >> 2) * 32 + j * 4 + (d & 3)] = v * r2;
        acc = fmaf(r2 * v, v, acc);   // same order as previous passing kernels
    }
    psq[p] = acc;
}

// ---------------- fused main: LDS x-tile; w via VMEM (vmcnt) broadcast loads.
// wid deliberately NOT readfirstlane'd: divergent-looking address keeps w loads
// on the vector path (global_load_dwordx4, vmcnt) so they pipeline independently
// of the x ds_reads (lgkmcnt). s_load+ds_read shared-lgkmcnt drains were the
// R12 stall (VALUBusy 47%).
__global__ __launch_bounds__(THREADS, 8) void grlvq_main(const float* __restrict__ x,
                                                         const float* __restrict__ wT,
                                                         const float* __restrict__ psq,
                                                         const float* __restrict__ pout,
                                                         float* __restrict__ out) {
    __shared__ float xs[ROWS * XSTRIDE];   // 33.8 KB
    __shared__ float red_s[ROWS * 8];      // per-wave best score
    __shared__ int   red_i[ROWS * 8];      // per-wave best index

    const int t = threadIdx.x;
    const int rowBase = blockIdx.x * ROWS;

    // stage x tile: 64 rows x 32 float4 = 2048 float4s; each of 512 threads loads 4
    #pragma unroll
    for (int k = 0; k < 4; ++k) {
        const int idx = t + k * THREADS;       // 0..2047
        const int r = idx >> 5, c = idx & 31;  // r in [0,64), c in [0,32)
        float4 v = *(const float4*)(x + (size_t)(rowBase + r) * DIM + c * 4);
        *(float4*)(&xs[r * XSTRIDE + c * 4]) = v;
    }
    __syncthreads();

    const int lane = t & 63;                  // = row in tile
    const int wid  = t >> 6;                  // stays in VGPR -> vector w loads
    const float* xrow  = &xs[lane * XSTRIDE];
    const float* wbase = wT + (size_t)wid * 8192;   // this wave's 64 protos
    const int pbase = wid * 64;

    float best = INFINITY;
    int bestIdx = pbase;

    #pragma unroll 1
    for (int oo = 0; oo < 8; ++oo) {                 // 8 octets of 8 protos
        float acc[8];
        #pragma unroll
        for (int j = 0; j < 8; ++j) acc[j] = 0.f;

        const float* wp = wbase + oo * 1024;
        #pragma unroll 4
        for (int c = 0; c < 32; ++c) {
            float4 xv = *(const float4*)(xrow + c * 4);   // ds_read_b128 (lgkmcnt)
            float4 wv[8];
            #pragma unroll
            for (int j = 0; j < 8; ++j)                   // global_load_dwordx4 (vmcnt),
                wv[j] = *(const float4*)(wp + c * 32 + j * 4);  // all lanes same addr -> bcast
            #pragma unroll
            for (int j = 0; j < 8; ++j) {
                acc[j] = fmaf(xv.x, wv[j].x, acc[j]);
                acc[j] = fmaf(xv.y, wv[j].y, acc[j]);
                acc[j] = fmaf(xv.z, wv[j].z, acc[j]);
                acc[j] = fmaf(xv.w, wv[j].w, acc[j]);
            }
        }

        #pragma unroll
        for (int j = 0; j < 8; ++j) {
            float s = psq[pbase + oo * 8 + j] - 2.0f * acc[j];
            if (s < best) { best = s; bestIdx = pbase + oo * 8 + j; }  // strict < ascending
        }
    }

    red_s[lane * 8 + wid] = best;
    red_i[lane * 8 + wid] = bestIdx;
    __syncthreads();

    if (t < ROWS) {                       // wave 0: lane = row
        float b = INFINITY;
        int bi = 0;
        #pragma unroll
        for (int w8 = 0; w8 < 8; ++w8) {  // ascending wave = ascending proto => first-min
            float s = red_s[t * 8 + w8];
            int  id = red_i[t * 8 + w8];
            if (s < b) { b = s; bi = id; }
        }
        const float4* po = (const float4*)(pout + (size_t)bi * ODIM);
        float4* op = (float4*)(out + (size_t)(rowBase + t) * ODIM);
        op[0] = po[0];
        op[1] = po[1];
    }
}

extern "C" void kernel_launch(void* const* d_in, const int* in_sizes, int n_in,
                              void* d_out, int out_size, void* d_ws, size_t ws_size,
                              hipStream_t stream) {
    const float* x     = (const float*)d_in[0];  // [BATCH, DIM]
    const float* proto = (const float*)d_in[1];  // [NPROTO, DIM]
    const float* pout  = (const float*)d_in[2];  // [NPROTO, ODIM]
    const float* rel   = (const float*)d_in[3];  // [DIM]
    float* out = (float*)d_out;                  // [BATCH, ODIM]

    float* wT  = (float*)d_ws;                   // NPROTO*DIM floats (256 KB)
    float* psq = wT + NPROTO * DIM;              // NPROTO floats

    grlvq_prep<<<(NPROTO + 127) / 128, 128, 0, stream>>>(proto, rel, wT, psq);
    grlvq_main<<<BATCH / ROWS, THREADS, 0, stream>>>(x, wT, psq, pout, out);
}

// Round 14
// 178.263 us; speedup vs baseline: 3.0030x; 3.0030x over previous
//
#include <hip/hip_runtime.h>

#define BATCH 65536
#define DIM 128
#define NPROTO 512
#define ODIM 8

#define ROWS 128           // rows per block; lane covers rows (lane) and (lane+64)
#define THREADS 512        // 8 waves; wave w owns protos [w*64, w*64+64)

// wT layout: proto p = wb*64 + oo*8 + j ; dim d = c*4 + d'
// offset(p,d) = wb*8192 + oo*1024 + c*32 + j*4 + d'

// ---------------- prep: pack w = proto*rel^2 into wT; psq[p] = sum_d rel^2*proto^2
// float4 loads/stores; accumulate chain kept in exact d-ascending fmaf order
// (bitwise-identical psq/wT vs the scalar version that passed).
__global__ void grlvq_prep(const float* __restrict__ proto,
                           const float* __restrict__ rel,
                           float* __restrict__ wT,
                           float* __restrict__ psq) {
    int p = blockIdx.x * blockDim.x + threadIdx.x;
    if (p >= NPROTO) return;
    const int wb = p >> 6, oo = (p >> 3) & 7, j = p & 7;
    float* wout = wT + wb * 8192 + oo * 1024 + j * 4;
    float acc = 0.f;
    #pragma unroll 8
    for (int c = 0; c < 32; ++c) {
        float4 rv = *(const float4*)(rel + c * 4);
        float4 pv = *(const float4*)(proto + (size_t)p * DIM + c * 4);
        float4 o;
        float r2;
        r2 = rv.x * rv.x; o.x = pv.x * r2; acc = fmaf(r2 * pv.x, pv.x, acc);
        r2 = rv.y * rv.y; o.y = pv.y * r2; acc = fmaf(r2 * pv.y, pv.y, acc);
        r2 = rv.z * rv.z; o.z = pv.z * r2; acc = fmaf(r2 * pv.z, pv.z, acc);
        r2 = rv.w * rv.w; o.w = pv.w * r2; acc = fmaf(r2 * pv.w, pv.w, acc);
        *(float4*)(wout + c * 32) = o;
    }
    psq[p] = acc;
}

// ---------------- fused main: 128 rows/block (2 per lane), LDS x as [c][r] float4
// (lane stride 16B -> conflict-free b128 read AND write), w via wave-uniform
// s_load; 128 FMA-issue-cycles per 128B of w (2x R12) halves scalar-pipe demand.
__global__ __launch_bounds__(THREADS, 4) void grlvq_main(const float* __restrict__ x,
                                                         const float* __restrict__ wT,
                                                         const float* __restrict__ psq,
                                                         const float* __restrict__ pout,
                                                         float* __restrict__ out) {
    __shared__ __align__(16) char smem[65536];   // xs (64 KB), red arrays unioned after compute
    float4* xs4  = (float4*)smem;                // [c][r] : c in [0,32), r in [0,128)
    float*  red_s = (float*)smem;                // [128][8]  (reused)
    int*    red_i = (int*)(smem + 4096);         // [128][8]

    const int t = threadIdx.x;
    const int rowBase = blockIdx.x * ROWS;

    // stage x: thread (r = t&127, cbase = t>>7) loads c = cbase+4k, k=0..7.
    // LDS writes: consecutive lanes -> consecutive r -> 16B stride, conflict-free.
    {
        const int r = t & 127;
        const int cbase = t >> 7;
        const float4* xg = (const float4*)(x + (size_t)(rowBase + r) * DIM);
        #pragma unroll
        for (int k = 0; k < 8; ++k) {
            const int c = cbase + 4 * k;
            xs4[c * 128 + r] = xg[c];
        }
    }
    __syncthreads();

    const int lane = t & 63;                                   // rows lane, lane+64
    const int wid  = __builtin_amdgcn_readfirstlane(t >> 6);   // SGPR -> uniform w addr
    const float* wbase = wT + (size_t)wid * 8192;              // this wave's 64 protos
    const int pbase = wid * 64;

    float bestA = INFINITY, bestB = INFINITY;
    int idxA = pbase, idxB = pbase;

    #pragma unroll 1
    for (int oo = 0; oo < 8; ++oo) {                 // 8 octets of 8 protos
        float accA[8], accB[8];
        #pragma unroll
        for (int j = 0; j < 8; ++j) { accA[j] = 0.f; accB[j] = 0.f; }

        const float* wp = wbase + oo * 1024;
        #pragma unroll 4
        for (int c = 0; c < 32; ++c) {
            float4 xa = xs4[c * 128 + lane];          // ds_read_b128, conflict-free
            float4 xb = xs4[c * 128 + lane + 64];
            const float* wc = wp + c * 32;            // uniform -> s_load (128B)
            #pragma unroll
            for (int j = 0; j < 8; ++j) {
                float w0 = wc[j * 4 + 0], w1 = wc[j * 4 + 1];
                float w2 = wc[j * 4 + 2], w3 = wc[j * 4 + 3];
                accA[j] = fmaf(xa.x, w0, accA[j]);
                accA[j] = fmaf(xa.y, w1, accA[j]);
                accA[j] = fmaf(xa.z, w2, accA[j]);
                accA[j] = fmaf(xa.w, w3, accA[j]);
                accB[j] = fmaf(xb.x, w0, accB[j]);
                accB[j] = fmaf(xb.y, w1, accB[j]);
                accB[j] = fmaf(xb.z, w2, accB[j]);
                accB[j] = fmaf(xb.w, w3, accB[j]);
            }
        }

        #pragma unroll
        for (int j = 0; j < 8; ++j) {
            float pq = psq[pbase + oo * 8 + j];
            float sA = pq - 2.0f * accA[j];
            float sB = pq - 2.0f * accB[j];
            if (sA < bestA) { bestA = sA; idxA = pbase + oo * 8 + j; }  // strict < ascending
            if (sB < bestB) { bestB = sB; idxB = pbase + oo * 8 + j; }
        }
    }

    __syncthreads();   // all waves done reading xs -> safe to reuse smem for reduction

    red_s[lane * 8 + wid] = bestA;        red_i[lane * 8 + wid] = idxA;
    red_s[(lane + 64) * 8 + wid] = bestB; red_i[(lane + 64) * 8 + wid] = idxB;
    __syncthreads();

    if (t < ROWS) {
        float b = INFINITY;
        int bi = 0;
        #pragma unroll
        for (int w8 = 0; w8 < 8; ++w8) {  // ascending wave = ascending proto => first-min
            float s = red_s[t * 8 + w8];
            int  id = red_i[t * 8 + w8];
            if (s < b) { b = s; bi = id; }
        }
        const float4* po = (const float4*)(pout + (size_t)bi * ODIM);
        float4* op = (float4*)(out + (size_t)(rowBase + t) * ODIM);
        op[0] = po[0];
        op[1] = po[1];
    }
}

extern "C" void kernel_launch(void* const* d_in, const int* in_sizes, int n_in,
                              void* d_out, int out_size, void* d_ws, size_t ws_size,
                              hipStream_t stream) {
    const float* x     = (const float*)d_in[0];  // [BATCH, DIM]
    const float* proto = (const float*)d_in[1];  // [NPROTO, DIM]
    const float* pout  = (const float*)d_in[2];  // [NPROTO, ODIM]
    const float* rel   = (const float*)d_in[3];  // [DIM]
    float* out = (float*)d_out;                  // [BATCH, ODIM]

    float* wT  = (float*)d_ws;                   // NPROTO*DIM floats (256 KB)
    float* psq = wT + NPROTO * DIM;              // NPROTO floats

    grlvq_prep<<<2, 256, 0, stream>>>(proto, rel, wT, psq);
    grlvq_main<<<BATCH / ROWS, THREADS, 0, stream>>>(x, wT, psq, pout, out);
}

// Round 15
// 171.682 us; speedup vs baseline: 3.1182x; 1.0383x over previous
//
#include <hip/hip_runtime.h>

#define BATCH 65536
#define DIM 128
#define NPROTO 512
#define ODIM 8

#define ROWS 128           // rows per block; lane covers rows (lane) and (lane+64)
#define THREADS 512        // 8 waves; wave w owns protos [w*64, w*64+64)

// wT layout: proto p = wb*64 + oo*8 + j ; dim d = c*4 + d'
// offset(p,d) = wb*8192 + oo*1024 + c*32 + j*4 + d'

// ---------------- prep_w: thread = (p, c). Coalesced proto reads (consecutive
// threads -> consecutive 16B of one proto row). Writes 16B each into wT.
__global__ void grlvq_prep_w(const float* __restrict__ proto,
                             const float* __restrict__ rel,
                             float* __restrict__ wT) {
    const int tid = blockIdx.x * 256 + threadIdx.x;   // 0..16383
    const int p = tid >> 5, c = tid & 31;
    const int wb = p >> 6, oo = (p >> 3) & 7, j = p & 7;
    float4 rv = *(const float4*)(rel + c * 4);
    float4 pv = *(const float4*)(proto + (size_t)p * DIM + c * 4);
    float4 o;
    o.x = pv.x * (rv.x * rv.x);
    o.y = pv.y * (rv.y * rv.y);
    o.z = pv.z * (rv.z * rv.z);
    o.w = pv.w * (rv.w * rv.w);
    *(float4*)(wT + wb * 8192 + oo * 1024 + c * 32 + j * 4) = o;
}

// ---------------- prep_psq: serial per-proto chain, EXACT same fmaf order as the
// passing kernels (bitwise-identical psq). 8 blocks x 64 threads.
__global__ void grlvq_prep_psq(const float* __restrict__ proto,
                               const float* __restrict__ rel,
                               float* __restrict__ psq) {
    const int p = blockIdx.x * 64 + threadIdx.x;
    float acc = 0.f;
    #pragma unroll 8
    for (int c = 0; c < 32; ++c) {
        float4 rv = *(const float4*)(rel + c * 4);
        float4 pv = *(const float4*)(proto + (size_t)p * DIM + c * 4);
        float r2;
        r2 = rv.x * rv.x; acc = fmaf(r2 * pv.x, pv.x, acc);
        r2 = rv.y * rv.y; acc = fmaf(r2 * pv.y, pv.y, acc);
        r2 = rv.z * rv.z; acc = fmaf(r2 * pv.z, pv.z, acc);
        r2 = rv.w * rv.w; acc = fmaf(r2 * pv.w, pv.w, acc);
    }
    psq[p] = acc;
}

// ---------------- fused main: 128 rows/block (2/lane), LDS x as [c][r] float4,
// w via wave-uniform s_load, 2 octets (16 protos) per accumulator pass:
// 256B scalar data feeds 256 FMA-issue-cycles; 2 independent s_load streams.
__global__ __launch_bounds__(THREADS, 4) void grlvq_main(const float* __restrict__ x,
                                                         const float* __restrict__ wT,
                                                         const float* __restrict__ psq,
                                                         const float* __restrict__ pout,
                                                         float* __restrict__ out) {
    __shared__ __align__(16) char smem[65536];   // xs (64 KB); red arrays union after compute
    float4* xs4  = (float4*)smem;                // [c][r] : c in [0,32), r in [0,128)
    float*  red_s = (float*)smem;                // [128][8]  (reused)
    int*    red_i = (int*)(smem + 4096);         // [128][8]

    const int t = threadIdx.x;
    const int rowBase = blockIdx.x * ROWS;

    // stage x: thread (r = t&127, cbase = t>>7) loads c = cbase+4k, k=0..7.
    {
        const int r = t & 127;
        const int cbase = t >> 7;
        const float4* xg = (const float4*)(x + (size_t)(rowBase + r) * DIM);
        #pragma unroll
        for (int k = 0; k < 8; ++k) {
            const int c = cbase + 4 * k;
            xs4[c * 128 + r] = xg[c];
        }
    }
    __syncthreads();

    const int lane = t & 63;                                   // rows lane, lane+64
    const int wid  = __builtin_amdgcn_readfirstlane(t >> 6);   // SGPR -> uniform w addr
    const float* wbase = wT + (size_t)wid * 8192;              // this wave's 64 protos
    const int pbase = wid * 64;

    float bestA = INFINITY, bestB = INFINITY;
    int idxA = pbase, idxB = pbase;

    #pragma unroll 1
    for (int oo2 = 0; oo2 < 4; ++oo2) {              // 4 passes x 16 protos
        float accA[16], accB[16];
        #pragma unroll
        for (int j = 0; j < 16; ++j) { accA[j] = 0.f; accB[j] = 0.f; }

        const float* wp0 = wbase + oo2 * 2048;        // even octet
        const float* wp1 = wp0 + 1024;                // odd octet
        #pragma unroll 8
        for (int c = 0; c < 32; ++c) {
            float4 xa = xs4[c * 128 + lane];          // ds_read_b128, imm offsets
            float4 xb = xs4[c * 128 + lane + 64];
            const float* wc0 = wp0 + c * 32;          // uniform -> s_load (128B)
            const float* wc1 = wp1 + c * 32;          // second independent stream
            #pragma unroll
            for (int j = 0; j < 8; ++j) {
                float w0 = wc0[j * 4 + 0], w1 = wc0[j * 4 + 1];
                float w2 = wc0[j * 4 + 2], w3 = wc0[j * 4 + 3];
                accA[j] = fmaf(xa.x, w0, accA[j]);
                accA[j] = fmaf(xa.y, w1, accA[j]);
                accA[j] = fmaf(xa.z, w2, accA[j]);
                accA[j] = fmaf(xa.w, w3, accA[j]);
                accB[j] = fmaf(xb.x, w0, accB[j]);
                accB[j] = fmaf(xb.y, w1, accB[j]);
                accB[j] = fmaf(xb.z, w2, accB[j]);
                accB[j] = fmaf(xb.w, w3, accB[j]);
            }
            #pragma unroll
            for (int j = 0; j < 8; ++j) {
                float w0 = wc1[j * 4 + 0], w1 = wc1[j * 4 + 1];
                float w2 = wc1[j * 4 + 2], w3 = wc1[j * 4 + 3];
                accA[8 + j] = fmaf(xa.x, w0, accA[8 + j]);
                accA[8 + j] = fmaf(xa.y, w1, accA[8 + j]);
                accA[8 + j] = fmaf(xa.z, w2, accA[8 + j]);
                accA[8 + j] = fmaf(xa.w, w3, accA[8 + j]);
                accB[8 + j] = fmaf(xb.x, w0, accB[8 + j]);
                accB[8 + j] = fmaf(xb.y, w1, accB[8 + j]);
                accB[8 + j] = fmaf(xb.z, w2, accB[8 + j]);
                accB[8 + j] = fmaf(xb.w, w3, accB[8 + j]);
            }
        }

        #pragma unroll
        for (int j = 0; j < 16; ++j) {                // proto = pbase + oo2*16 + j (ascending)
            float pq = psq[pbase + oo2 * 16 + j];
            float sA = pq - 2.0f * accA[j];
            float sB = pq - 2.0f * accB[j];
            if (sA < bestA) { bestA = sA; idxA = pbase + oo2 * 16 + j; }
            if (sB < bestB) { bestB = sB; idxB = pbase + oo2 * 16 + j; }
        }
    }

    __syncthreads();   // all waves done reading xs -> safe to reuse smem

    red_s[lane * 8 + wid] = bestA;        red_i[lane * 8 + wid] = idxA;
    red_s[(lane + 64) * 8 + wid] = bestB; red_i[(lane + 64) * 8 + wid] = idxB;
    __syncthreads();

    if (t < ROWS) {
        float b = INFINITY;
        int bi = 0;
        #pragma unroll
        for (int w8 = 0; w8 < 8; ++w8) {  // ascending wave = ascending proto => first-min
            float s = red_s[t * 8 + w8];
            int  id = red_i[t * 8 + w8];
            if (s < b) { b = s; bi = id; }
        }
        const float4* po = (const float4*)(pout + (size_t)bi * ODIM);
        float4* op = (float4*)(out + (size_t)(rowBase + t) * ODIM);
        op[0] = po[0];
        op[1] = po[1];
    }
}

extern "C" void kernel_launch(void* const* d_in, const int* in_sizes, int n_in,
                              void* d_out, int out_size, void* d_ws, size_t ws_size,
                              hipStream_t stream) {
    const float* x     = (const float*)d_in[0];  // [BATCH, DIM]
    const float* proto = (const float*)d_in[1];  // [NPROTO, DIM]
    const float* pout  = (const float*)d_in[2];  // [NPROTO, ODIM]
    const float* rel   = (const float*)d_in[3];  // [DIM]
    float* out = (float*)d_out;                  // [BATCH, ODIM]

    float* wT  = (float*)d_ws;                   // NPROTO*DIM floats (256 KB)
    float* psq = wT + NPROTO * DIM;              // NPROTO floats

    grlvq_prep_w<<<64, 256, 0, stream>>>(proto, rel, wT);
    grlvq_prep_psq<<<8, 64, 0, stream>>>(proto, rel, psq);
    grlvq_main<<<BATCH / ROWS, THREADS, 0, stream>>>(x, wT, psq, pout, out);
}